// Round 6
// baseline (326.672 us; speedup 1.0000x reference)
//
#include <hip/hip_runtime.h>
#include <hip/hip_bf16.h>

#define NROWS  8192
#define DIM    256
#define NCLASS 512
#define MARGIN 0.3f

using bf16x8 = __attribute__((ext_vector_type(8))) short;
using f32x4  = __attribute__((ext_vector_type(4))) float;

__device__ inline ushort f2bf(float f) {
    __hip_bfloat16 h = __float2bfloat16(f);
    return *reinterpret_cast<ushort*>(&h);
}
__device__ inline float bf2f(ushort u) {
    return __uint_as_float(((unsigned)u) << 16);
}
// Order-preserving float<->uint transform: bitwise atomicMax/Min == float max/min.
__device__ inline unsigned f2ord(float f) {
    unsigned b = __float_as_uint(f);
    return (b & 0x80000000u) ? ~b : (b | 0x80000000u);
}
__device__ inline float ord2f(unsigned u) {
    return __uint_as_float((u & 0x80000000u) ? (u & 0x7FFFFFFFu) : ~u);
}
__device__ inline void ld16_g2l(const void* g, void* l) {
    __builtin_amdgcn_global_load_lds(
        (const __attribute__((address_space(1))) unsigned int*)g,
        (__attribute__((address_space(3))) unsigned int*)l, 16, 0, 0);
}

// ---- workspace layout (bytes) ----
#define XBS_OFF 0u            // 4 MB   class-sorted bf16 rows
#define SQS_OFF 4194304u      // 32 KB  sorted ||x||^2
#define TGT_OFF 4227072u      // 32 KB  sorted targets
#define PMX_OFF 4259840u      // 32 KB  ordered-uint max over positives of (sqc-2acc)
#define NMN_OFF 4292608u      // 32 KB  ordered-uint min over negatives
#define BIN_OFF 4325376u      // 2 KB   class bin cursors
#define ACC_OFF 4327424u      // 8      double loss accumulator
#define TIK_OFF 4327432u      // 4      completion ticket

// K1: one block. Histogram of targets -> exclusive scan -> bin cursors.
__global__ __launch_bounds__(512) void hist_scan_kernel(
    const int* __restrict__ tgt, int* __restrict__ bincur,
    double* __restrict__ accd, unsigned* __restrict__ ticket)
{
    __shared__ int h[NCLASS];
    int tid = threadIdx.x;
    h[tid] = 0;
    if (tid == 0) { *accd = 0.0; *ticket = 0u; }
    __syncthreads();
    for (int k = 0; k < NROWS / NCLASS; ++k)
        atomicAdd(&h[tgt[tid + k * NCLASS]], 1);
    __syncthreads();
    int cnt = h[tid];
    for (int ofs = 1; ofs < NCLASS; ofs <<= 1) {
        int v = (tid >= ofs) ? h[tid - ofs] : 0;
        __syncthreads();
        h[tid] += v;
        __syncthreads();
    }
    bincur[tid] = h[tid] - cnt;  // exclusive start of class tid
}

// K2: one wave per row. Normalize fp32 -> bf16, scatter to class-sorted slot.
__global__ __launch_bounds__(256) void norm_scatter_kernel(
    const float* __restrict__ in, const int* __restrict__ tgt,
    int* __restrict__ bincur, ushort* __restrict__ xbs,
    float* __restrict__ sqs, int* __restrict__ tgts,
    unsigned* __restrict__ pmax, unsigned* __restrict__ nmin)
{
    int row  = blockIdx.x * 4 + (threadIdx.x >> 6);
    int lane = threadIdx.x & 63;
    float4 v = ((const float4*)(in + (size_t)row * DIM))[lane];
    float ss = v.x * v.x + v.y * v.y + v.z * v.z + v.w * v.w;
#pragma unroll
    for (int m = 1; m < 64; m <<= 1) ss += __shfl_xor(ss, m, 64);
    float inv = 1.0f / (sqrtf(ss) + 1e-12f);

    ushort4 st;
    st.x = f2bf(v.x * inv); st.y = f2bf(v.y * inv);
    st.z = f2bf(v.z * inv); st.w = f2bf(v.w * inv);

    int t = 0, dst = 0;
    if (lane == 0) { t = tgt[row]; dst = atomicAdd(&bincur[t], 1); }
    dst = __shfl(dst, 0); t = __shfl(t, 0);

    ((ushort4*)(xbs + (size_t)dst * DIM))[lane] = st;

    float a0 = bf2f(st.x), a1 = bf2f(st.y), a2 = bf2f(st.z), a3 = bf2f(st.w);
    float s2 = a0 * a0 + a1 * a1 + a2 * a2 + a3 * a3;
#pragma unroll
    for (int m = 1; m < 64; m <<= 1) s2 += __shfl_xor(s2, m, 64);
    if (lane == 0) {
        sqs[dst]  = s2;
        tgts[dst] = t;
        pmax[dst] = 0x007FFFFFu;  // f2ord(-inf)
        nmin[dst] = 0xFF800000u;  // f2ord(+inf)
    }
}

// K3: fused gram + hard-pos/hard-neg. Block: 4 waves, 256 rows x 256 cols.
// Grid (32,32) = 1024 blocks = 4 blocks/CU (LDS 35.8KB, VGPR<=128 both permit 4):
// the extra co-resident blocks hide the per-stage __syncthreads + ds_read
// latency that capped round 3 at 2 blocks/CU. B double-buffered in LDS
// (32 cols = 16KB/stage, 8 stages), xor-swizzled; prefetch issued a full
// stage ahead so the barrier's vmcnt drain is free. Class-sorted rows: tiles
// with no class overlap take the 2-op/element negative-only epilogue.
__global__ __launch_bounds__(256, 4) void gram_kernel(
    const ushort* __restrict__ xbs, const float* __restrict__ sqs,
    const int* __restrict__ tgts, unsigned* __restrict__ pmax,
    unsigned* __restrict__ nmin)
{
    __shared__ struct {
        char  buf[2][16384];   // stage buffers: 32 cols x 512B, 16B-chunk swizzled
        float sqc[256];        // per-col ||x||^2 for this 256-col chunk
        int   tgc[256];        // per-col class
        int   tga[256];        // per-row class for block's 256 rows
    } sm;

    const int wave = threadIdx.x >> 6;
    const int lane = threadIdx.x & 63;
    const int l15  = lane & 15;
    const int quad = lane >> 4;
    const int mbase = blockIdx.x * 256 + wave * 64;
    const int nbase = blockIdx.y * 256;

    {   // stage metadata for the chunk
        int c = threadIdx.x;
        sm.sqc[c] = sqs[nbase + c];
        sm.tgc[c] = tgts[nbase + c];
        sm.tga[c] = tgts[blockIdx.x * 256 + c];
    }

    // Preload A fragments: 4 tiles x full K=256 (sorted storage, direct).
    bf16x8 afrag[4][8];
#pragma unroll
    for (int a = 0; a < 4; ++a) {
        const ushort* arow = xbs + (size_t)(mbase + a * 16 + l15) * DIM + quad * 8;
#pragma unroll
        for (int kk = 0; kk < 8; ++kk)
            afrag[a][kk] = *(const bf16x8*)(arow + kk * 32);
    }
    const int rlo = tgts[mbase];
    const int rhi = tgts[mbase + 63];

    // DMA source offsets (xor-swizzle compensated on the global address):
    // region i holds cols {2i,2i+1}; lane writes +lane*16; physical slot c31 of
    // col (2i+colh) holds logical chunk c31^(col&7).
    const int colh = lane >> 5, c31 = lane & 31;
    int offs[4];
#pragma unroll
    for (int j = 0; j < 4; ++j)
        offs[j] = colh * 512 + ((c31 ^ ((2 * j + colh) & 7)) << 4);

    const char* xbs_b = (const char*)xbs;

    {   // prologue: DMA stage 0
        const char* gbase = xbs_b + (size_t)nbase * 512;
#pragma unroll
        for (int j = 0; j < 4; ++j) {
            int i = wave * 4 + j;
            ld16_g2l(gbase + i * 1024 + offs[j], sm.buf[0] + i * 1024);
        }
    }
    __syncthreads();   // drains prologue DMA + metadata stores

    float pm[16], nm[16];
#pragma unroll
    for (int j = 0; j < 16; ++j) { pm[j] = -__builtin_inff(); nm[j] = __builtin_inff(); }

#pragma unroll 2
    for (int s = 0; s < 8; ++s) {
        if (s < 7) {   // issue stage s+1; lands during this stage's compute
            const char* gbase = xbs_b + (size_t)(nbase + (s + 1) * 32) * 512;
            char* lbase = sm.buf[(s + 1) & 1];
#pragma unroll
            for (int j = 0; j < 4; ++j) {
                int i = wave * 4 + j;
                ld16_g2l(gbase + i * 1024 + offs[j], lbase + i * 1024);
            }
        }
        const char* bufc = sm.buf[s & 1];
#pragma unroll
        for (int u = 0; u < 2; ++u) {
            const int t16 = s * 32 + u * 16;
            bf16x8 bfrag[8];
#pragma unroll
            for (int kk = 0; kk < 8; ++kk)
                bfrag[kk] = *(const bf16x8*)(bufc + u * 8192 + l15 * 512 +
                                             (((quad + 4 * kk) ^ (l15 & 7)) << 4));
            f32x4 acc4[4];
#pragma unroll
            for (int a = 0; a < 4; ++a) {
                f32x4 acc = {0.f, 0.f, 0.f, 0.f};
#pragma unroll
                for (int kk = 0; kk < 8; ++kk)
                    acc = __builtin_amdgcn_mfma_f32_16x16x32_bf16(afrag[a][kk], bfrag[kk], acc, 0, 0, 0);
                acc4[a] = acc;
            }
            const float sqc = sm.sqc[t16 + l15];
            const int clo = sm.tgc[t16], chi = sm.tgc[t16 + 15];
            if (rlo <= chi && clo <= rhi) {
                const int tc = sm.tgc[t16 + l15];
#pragma unroll
                for (int a = 0; a < 4; ++a)
#pragma unroll
                    for (int i = 0; i < 4; ++i) {
                        const float v = fmaf(acc4[a][i], -2.0f, sqc);
                        const bool same = (sm.tga[wave * 64 + a * 16 + quad * 4 + i] == tc);
                        pm[a * 4 + i] = fmaxf(pm[a * 4 + i], same ? v : -__builtin_inff());
                        nm[a * 4 + i] = fminf(nm[a * 4 + i], same ? __builtin_inff() : v);
                    }
            } else {
#pragma unroll
                for (int a = 0; a < 4; ++a)
#pragma unroll
                    for (int i = 0; i < 4; ++i)
                        nm[a * 4 + i] = fminf(nm[a * 4 + i], fmaf(acc4[a][i], -2.0f, sqc));
            }
        }
        __syncthreads();
    }

    // Reduce across the 16 column-lanes, one atomic per row.
#pragma unroll
    for (int m = 1; m < 16; m <<= 1) {
#pragma unroll
        for (int j = 0; j < 16; ++j) {
            pm[j] = fmaxf(pm[j], __shfl_xor(pm[j], m, 64));
            nm[j] = fminf(nm[j], __shfl_xor(nm[j], m, 64));
        }
    }
    if (l15 == 0) {
#pragma unroll
        for (int a = 0; a < 4; ++a)
#pragma unroll
            for (int i = 0; i < 4; ++i) {
                int r = mbase + a * 16 + quad * 4 + i;
                atomicMax(&pmax[r], f2ord(pm[a * 4 + i]));
                atomicMin(&nmin[r], f2ord(nm[a * 4 + i]));
            }
    }
}

// K4: multi-block finalize, fp64 atomic accumulation + completion ticket.
__global__ __launch_bounds__(256) void finalize_kernel(
    const unsigned* __restrict__ pmax, const unsigned* __restrict__ nmin,
    const float* __restrict__ sqs, double* __restrict__ accd,
    unsigned* __restrict__ ticket, float* __restrict__ out)
{
    int r = blockIdx.x * 256 + threadIdx.x;
    float pe = ord2f(pmax[r]);
    float ne = ord2f(nmin[r]);
    float ap = sqrtf(fmaxf(sqs[r] + pe, 0.0f));
    float an = (ne > 1e30f) ? (MARGIN + 1.0f) : sqrtf(fmaxf(sqs[r] + ne, 0.0f));
    float h  = fmaxf(ap - an + MARGIN, 0.0f);
    double s = (double)h;
#pragma unroll
    for (int m = 1; m < 64; m <<= 1) s += __shfl_xor(s, m, 64);
    __shared__ double sh[4];
    if ((threadIdx.x & 63) == 0) sh[threadIdx.x >> 6] = s;
    __syncthreads();
    if (threadIdx.x == 0) {
        double b = sh[0] + sh[1] + sh[2] + sh[3];
        atomicAdd(accd, b);
        __threadfence();
        unsigned old = atomicAdd(ticket, 1u);
        if (old == gridDim.x - 1) {
            double total = atomicAdd(accd, 0.0);  // coherent read
            out[0] = (float)(total / (double)NROWS);
        }
    }
}

extern "C" void kernel_launch(void* const* d_in, const int* in_sizes, int n_in,
                              void* d_out, int out_size, void* d_ws, size_t ws_size,
                              hipStream_t stream) {
    const float* in  = (const float*)d_in[0];
    const int*   tgt = (const int*)d_in[1];
    float*       out = (float*)d_out;

    char* ws = (char*)d_ws;
    ushort*   xbs    = (ushort*)(ws + XBS_OFF);
    float*    sqs    = (float*)(ws + SQS_OFF);
    int*      tgts   = (int*)(ws + TGT_OFF);
    unsigned* pmax   = (unsigned*)(ws + PMX_OFF);
    unsigned* nmin   = (unsigned*)(ws + NMN_OFF);
    int*      bincur = (int*)(ws + BIN_OFF);
    double*   accd   = (double*)(ws + ACC_OFF);
    unsigned* ticket = (unsigned*)(ws + TIK_OFF);

    hist_scan_kernel<<<1, 512, 0, stream>>>(tgt, bincur, accd, ticket);
    norm_scatter_kernel<<<NROWS / 4, 256, 0, stream>>>(in, tgt, bincur, xbs, sqs, tgts, pmax, nmin);
    gram_kernel<<<dim3(32, 32), 256, 0, stream>>>(xbs, sqs, tgts, pmax, nmin);
    finalize_kernel<<<32, 256, 0, stream>>>(pmax, nmin, sqs, accd, ticket, out);
}

// Round 7
// 267.692 us; speedup vs baseline: 1.2203x; 1.2203x over previous
//
#include <hip/hip_runtime.h>
#include <hip/hip_bf16.h>

#define NROWS  8192
#define DIM    256
#define NCLASS 512
#define MARGIN 0.3f

using bf16x8 = __attribute__((ext_vector_type(8))) short;
using f32x4  = __attribute__((ext_vector_type(4))) float;

__device__ inline ushort f2bf(float f) {
    __hip_bfloat16 h = __float2bfloat16(f);
    return *reinterpret_cast<ushort*>(&h);
}
__device__ inline float bf2f(ushort u) {
    return __uint_as_float(((unsigned)u) << 16);
}
// Order-preserving float<->uint transform: bitwise atomicMax/Min == float max/min.
__device__ inline unsigned f2ord(float f) {
    unsigned b = __float_as_uint(f);
    return (b & 0x80000000u) ? ~b : (b | 0x80000000u);
}
__device__ inline float ord2f(unsigned u) {
    return __uint_as_float((u & 0x80000000u) ? (u & 0x7FFFFFFFu) : ~u);
}
__device__ inline void ld16_g2l(const void* g, void* l) {
    __builtin_amdgcn_global_load_lds(
        (const __attribute__((address_space(1))) unsigned int*)g,
        (__attribute__((address_space(3))) unsigned int*)l, 16, 0, 0);
}

// ---- workspace layout (bytes) ----
#define XBS_OFF 0u            // 4 MB   class-sorted bf16 rows
#define SQS_OFF 4194304u      // 32 KB  sorted ||x||^2
#define TGT_OFF 4227072u      // 32 KB  sorted targets
#define PMX_OFF 4259840u      // 32 KB  ordered-uint max over positives of (sqc-2acc)
#define NMN_OFF 4292608u      // 32 KB  ordered-uint min over negatives
#define BIN_OFF 4325376u      // 2 KB   class bin cursors
#define ACC_OFF 4327424u      // 8      double loss accumulator
#define TIK_OFF 4327432u      // 4      completion ticket

// K1: one block. Histogram of targets -> exclusive scan -> bin cursors.
__global__ __launch_bounds__(512) void hist_scan_kernel(
    const int* __restrict__ tgt, int* __restrict__ bincur,
    double* __restrict__ accd, unsigned* __restrict__ ticket)
{
    __shared__ int h[NCLASS];
    int tid = threadIdx.x;
    h[tid] = 0;
    if (tid == 0) { *accd = 0.0; *ticket = 0u; }
    __syncthreads();
    for (int k = 0; k < NROWS / NCLASS; ++k)
        atomicAdd(&h[tgt[tid + k * NCLASS]], 1);
    __syncthreads();
    int cnt = h[tid];
    for (int ofs = 1; ofs < NCLASS; ofs <<= 1) {
        int v = (tid >= ofs) ? h[tid - ofs] : 0;
        __syncthreads();
        h[tid] += v;
        __syncthreads();
    }
    bincur[tid] = h[tid] - cnt;  // exclusive start of class tid
}

// K2: one wave per row. Normalize fp32 -> bf16, scatter to class-sorted slot.
__global__ __launch_bounds__(256) void norm_scatter_kernel(
    const float* __restrict__ in, const int* __restrict__ tgt,
    int* __restrict__ bincur, ushort* __restrict__ xbs,
    float* __restrict__ sqs, int* __restrict__ tgts,
    unsigned* __restrict__ pmax, unsigned* __restrict__ nmin)
{
    int row  = blockIdx.x * 4 + (threadIdx.x >> 6);
    int lane = threadIdx.x & 63;
    float4 v = ((const float4*)(in + (size_t)row * DIM))[lane];
    float ss = v.x * v.x + v.y * v.y + v.z * v.z + v.w * v.w;
#pragma unroll
    for (int m = 1; m < 64; m <<= 1) ss += __shfl_xor(ss, m, 64);
    float inv = 1.0f / (sqrtf(ss) + 1e-12f);

    ushort4 st;
    st.x = f2bf(v.x * inv); st.y = f2bf(v.y * inv);
    st.z = f2bf(v.z * inv); st.w = f2bf(v.w * inv);

    int t = 0, dst = 0;
    if (lane == 0) { t = tgt[row]; dst = atomicAdd(&bincur[t], 1); }
    dst = __shfl(dst, 0); t = __shfl(t, 0);

    ((ushort4*)(xbs + (size_t)dst * DIM))[lane] = st;

    float a0 = bf2f(st.x), a1 = bf2f(st.y), a2 = bf2f(st.z), a3 = bf2f(st.w);
    float s2 = a0 * a0 + a1 * a1 + a2 * a2 + a3 * a3;
#pragma unroll
    for (int m = 1; m < 64; m <<= 1) s2 += __shfl_xor(s2, m, 64);
    if (lane == 0) {
        sqs[dst]  = s2;
        tgts[dst] = t;
        pmax[dst] = 0x007FFFFFu;  // f2ord(-inf)
        nmin[dst] = 0xFF800000u;  // f2ord(+inf)
    }
}

// K3: fused gram + hard-pos/hard-neg. Block: 4 waves, 256 rows x 256 cols.
// Grid (32,32) = 1024 blocks. __launch_bounds__(256,3): VGPR cap ~170 —
// comfortably above this body's ~130-reg demand, so NO spill (round 6's
// (256,4) forced VGPR=64 and spilled afrag to scratch: 840 MB HBM traffic,
// 258 us). 3 blocks/CU = 12 waves/CU hides the per-stage barrier + ds_read
// latency that capped round 3 (2 blocks/CU) at 46.7 us.
__global__ __launch_bounds__(256, 3) void gram_kernel(
    const ushort* __restrict__ xbs, const float* __restrict__ sqs,
    const int* __restrict__ tgts, unsigned* __restrict__ pmax,
    unsigned* __restrict__ nmin)
{
    __shared__ struct {
        char  buf[2][16384];   // stage buffers: 32 cols x 512B, 16B-chunk swizzled
        float sqc[256];        // per-col ||x||^2 for this 256-col chunk
        int   tgc[256];        // per-col class
        int   tga[256];        // per-row class for block's 256 rows
    } sm;

    const int wave = threadIdx.x >> 6;
    const int lane = threadIdx.x & 63;
    const int l15  = lane & 15;
    const int quad = lane >> 4;
    const int mbase = blockIdx.x * 256 + wave * 64;
    const int nbase = blockIdx.y * 256;

    {   // stage metadata for the chunk
        int c = threadIdx.x;
        sm.sqc[c] = sqs[nbase + c];
        sm.tgc[c] = tgts[nbase + c];
        sm.tga[c] = tgts[blockIdx.x * 256 + c];
    }

    // Preload A fragments: 4 tiles x full K=256 (sorted storage, direct).
    bf16x8 afrag[4][8];
#pragma unroll
    for (int a = 0; a < 4; ++a) {
        const ushort* arow = xbs + (size_t)(mbase + a * 16 + l15) * DIM + quad * 8;
#pragma unroll
        for (int kk = 0; kk < 8; ++kk)
            afrag[a][kk] = *(const bf16x8*)(arow + kk * 32);
    }
    const int rlo = tgts[mbase];
    const int rhi = tgts[mbase + 63];

    // DMA source offsets (xor-swizzle compensated on the global address):
    // region i holds cols {2i,2i+1}; lane writes +lane*16; physical slot c31 of
    // col (2i+colh) holds logical chunk c31^(col&7).
    const int colh = lane >> 5, c31 = lane & 31;
    int offs[4];
#pragma unroll
    for (int j = 0; j < 4; ++j)
        offs[j] = colh * 512 + ((c31 ^ ((2 * j + colh) & 7)) << 4);

    const char* xbs_b = (const char*)xbs;

    {   // prologue: DMA stage 0
        const char* gbase = xbs_b + (size_t)nbase * 512;
#pragma unroll
        for (int j = 0; j < 4; ++j) {
            int i = wave * 4 + j;
            ld16_g2l(gbase + i * 1024 + offs[j], sm.buf[0] + i * 1024);
        }
    }
    __syncthreads();   // drains prologue DMA + metadata stores

    float pm[16], nm[16];
#pragma unroll
    for (int j = 0; j < 16; ++j) { pm[j] = -__builtin_inff(); nm[j] = __builtin_inff(); }

#pragma unroll 2
    for (int s = 0; s < 8; ++s) {
        if (s < 7) {   // issue stage s+1; lands during this stage's compute
            const char* gbase = xbs_b + (size_t)(nbase + (s + 1) * 32) * 512;
            char* lbase = sm.buf[(s + 1) & 1];
#pragma unroll
            for (int j = 0; j < 4; ++j) {
                int i = wave * 4 + j;
                ld16_g2l(gbase + i * 1024 + offs[j], lbase + i * 1024);
            }
        }
        const char* bufc = sm.buf[s & 1];
#pragma unroll
        for (int u = 0; u < 2; ++u) {
            const int t16 = s * 32 + u * 16;
            bf16x8 bfrag[8];
#pragma unroll
            for (int kk = 0; kk < 8; ++kk)
                bfrag[kk] = *(const bf16x8*)(bufc + u * 8192 + l15 * 512 +
                                             (((quad + 4 * kk) ^ (l15 & 7)) << 4));
            f32x4 acc4[4];
#pragma unroll
            for (int a = 0; a < 4; ++a) {
                f32x4 acc = {0.f, 0.f, 0.f, 0.f};
#pragma unroll
                for (int kk = 0; kk < 8; ++kk)
                    acc = __builtin_amdgcn_mfma_f32_16x16x32_bf16(afrag[a][kk], bfrag[kk], acc, 0, 0, 0);
                acc4[a] = acc;
            }
            const float sqc = sm.sqc[t16 + l15];
            const int clo = sm.tgc[t16], chi = sm.tgc[t16 + 15];
            if (rlo <= chi && clo <= rhi) {
                const int tc = sm.tgc[t16 + l15];
#pragma unroll
                for (int a = 0; a < 4; ++a)
#pragma unroll
                    for (int i = 0; i < 4; ++i) {
                        const float v = fmaf(acc4[a][i], -2.0f, sqc);
                        const bool same = (sm.tga[wave * 64 + a * 16 + quad * 4 + i] == tc);
                        pm[a * 4 + i] = fmaxf(pm[a * 4 + i], same ? v : -__builtin_inff());
                        nm[a * 4 + i] = fminf(nm[a * 4 + i], same ? __builtin_inff() : v);
                    }
            } else {
#pragma unroll
                for (int a = 0; a < 4; ++a)
#pragma unroll
                    for (int i = 0; i < 4; ++i)
                        nm[a * 4 + i] = fminf(nm[a * 4 + i], fmaf(acc4[a][i], -2.0f, sqc));
            }
        }
        __syncthreads();
    }

    // Reduce across the 16 column-lanes, one atomic per row.
#pragma unroll
    for (int m = 1; m < 16; m <<= 1) {
#pragma unroll
        for (int j = 0; j < 16; ++j) {
            pm[j] = fmaxf(pm[j], __shfl_xor(pm[j], m, 64));
            nm[j] = fminf(nm[j], __shfl_xor(nm[j], m, 64));
        }
    }
    if (l15 == 0) {
#pragma unroll
        for (int a = 0; a < 4; ++a)
#pragma unroll
            for (int i = 0; i < 4; ++i) {
                int r = mbase + a * 16 + quad * 4 + i;
                atomicMax(&pmax[r], f2ord(pm[a * 4 + i]));
                atomicMin(&nmin[r], f2ord(nm[a * 4 + i]));
            }
    }
}

// K4: multi-block finalize, fp64 atomic accumulation + completion ticket.
__global__ __launch_bounds__(256) void finalize_kernel(
    const unsigned* __restrict__ pmax, const unsigned* __restrict__ nmin,
    const float* __restrict__ sqs, double* __restrict__ accd,
    unsigned* __restrict__ ticket, float* __restrict__ out)
{
    int r = blockIdx.x * 256 + threadIdx.x;
    float pe = ord2f(pmax[r]);
    float ne = ord2f(nmin[r]);
    float ap = sqrtf(fmaxf(sqs[r] + pe, 0.0f));
    float an = (ne > 1e30f) ? (MARGIN + 1.0f) : sqrtf(fmaxf(sqs[r] + ne, 0.0f));
    float h  = fmaxf(ap - an + MARGIN, 0.0f);
    double s = (double)h;
#pragma unroll
    for (int m = 1; m < 64; m <<= 1) s += __shfl_xor(s, m, 64);
    __shared__ double sh[4];
    if ((threadIdx.x & 63) == 0) sh[threadIdx.x >> 6] = s;
    __syncthreads();
    if (threadIdx.x == 0) {
        double b = sh[0] + sh[1] + sh[2] + sh[3];
        atomicAdd(accd, b);
        __threadfence();
        unsigned old = atomicAdd(ticket, 1u);
        if (old == gridDim.x - 1) {
            double total = atomicAdd(accd, 0.0);  // coherent read
            out[0] = (float)(total / (double)NROWS);
        }
    }
}

extern "C" void kernel_launch(void* const* d_in, const int* in_sizes, int n_in,
                              void* d_out, int out_size, void* d_ws, size_t ws_size,
                              hipStream_t stream) {
    const float* in  = (const float*)d_in[0];
    const int*   tgt = (const int*)d_in[1];
    float*       out = (float*)d_out;

    char* ws = (char*)d_ws;
    ushort*   xbs    = (ushort*)(ws + XBS_OFF);
    float*    sqs    = (float*)(ws + SQS_OFF);
    int*      tgts   = (int*)(ws + TGT_OFF);
    unsigned* pmax   = (unsigned*)(ws + PMX_OFF);
    unsigned* nmin   = (unsigned*)(ws + NMN_OFF);
    int*      bincur = (int*)(ws + BIN_OFF);
    double*   accd   = (double*)(ws + ACC_OFF);
    unsigned* ticket = (unsigned*)(ws + TIK_OFF);

    hist_scan_kernel<<<1, 512, 0, stream>>>(tgt, bincur, accd, ticket);
    norm_scatter_kernel<<<NROWS / 4, 256, 0, stream>>>(in, tgt, bincur, xbs, sqs, tgts, pmax, nmin);
    gram_kernel<<<dim3(32, 32), 256, 0, stream>>>(xbs, sqs, tgts, pmax, nmin);
    finalize_kernel<<<32, 256, 0, stream>>>(pmax, nmin, sqs, accd, ticket, out);
}

// Round 8
// 115.806 us; speedup vs baseline: 2.8209x; 2.3116x over previous
//
#include <hip/hip_runtime.h>
#include <hip/hip_bf16.h>

#define NROWS  8192
#define DIM    256
#define NCLASS 512
#define MARGIN 0.3f

using bf16x8 = __attribute__((ext_vector_type(8))) short;
using f32x4  = __attribute__((ext_vector_type(4))) float;

__device__ inline ushort f2bf(float f) {
    __hip_bfloat16 h = __float2bfloat16(f);
    return *reinterpret_cast<ushort*>(&h);
}
__device__ inline float bf2f(ushort u) {
    return __uint_as_float(((unsigned)u) << 16);
}
// Order-preserving float<->uint transform: bitwise atomicMax/Min == float max/min.
__device__ inline unsigned f2ord(float f) {
    unsigned b = __float_as_uint(f);
    return (b & 0x80000000u) ? ~b : (b | 0x80000000u);
}
__device__ inline float ord2f(unsigned u) {
    return __uint_as_float((u & 0x80000000u) ? (u & 0x7FFFFFFFu) : ~u);
}
__device__ inline void ld16_g2l(const void* g, void* l) {
    __builtin_amdgcn_global_load_lds(
        (const __attribute__((address_space(1))) unsigned int*)g,
        (__attribute__((address_space(3))) unsigned int*)l, 16, 0, 0);
}

// ---- workspace layout (bytes) ----
#define XBS_OFF 0u            // 4 MB   class-sorted bf16 rows
#define SQS_OFF 4194304u      // 32 KB  sorted ||x||^2
#define TGT_OFF 4227072u      // 32 KB  sorted targets
#define PMX_OFF 4259840u      // 32 KB  ordered-uint max over positives of (sqc-2acc)
#define NMN_OFF 4292608u      // 32 KB  ordered-uint min over negatives
#define BIN_OFF 4325376u      // 2 KB   class bin cursors
#define ACC_OFF 4327424u      // 8      double loss accumulator
#define TIK_OFF 4327432u      // 4      completion ticket

// K1: one block. Histogram of targets -> exclusive scan -> bin cursors.
__global__ __launch_bounds__(512) void hist_scan_kernel(
    const int* __restrict__ tgt, int* __restrict__ bincur,
    double* __restrict__ accd, unsigned* __restrict__ ticket)
{
    __shared__ int h[NCLASS];
    int tid = threadIdx.x;
    h[tid] = 0;
    if (tid == 0) { *accd = 0.0; *ticket = 0u; }
    __syncthreads();
    for (int k = 0; k < NROWS / NCLASS; ++k)
        atomicAdd(&h[tgt[tid + k * NCLASS]], 1);
    __syncthreads();
    int cnt = h[tid];
    for (int ofs = 1; ofs < NCLASS; ofs <<= 1) {
        int v = (tid >= ofs) ? h[tid - ofs] : 0;
        __syncthreads();
        h[tid] += v;
        __syncthreads();
    }
    bincur[tid] = h[tid] - cnt;  // exclusive start of class tid
}

// K2: one wave per row. Normalize fp32 -> bf16, scatter to class-sorted slot.
__global__ __launch_bounds__(256) void norm_scatter_kernel(
    const float* __restrict__ in, const int* __restrict__ tgt,
    int* __restrict__ bincur, ushort* __restrict__ xbs,
    float* __restrict__ sqs, int* __restrict__ tgts,
    unsigned* __restrict__ pmax, unsigned* __restrict__ nmin)
{
    int row  = blockIdx.x * 4 + (threadIdx.x >> 6);
    int lane = threadIdx.x & 63;
    float4 v = ((const float4*)(in + (size_t)row * DIM))[lane];
    float ss = v.x * v.x + v.y * v.y + v.z * v.z + v.w * v.w;
#pragma unroll
    for (int m = 1; m < 64; m <<= 1) ss += __shfl_xor(ss, m, 64);
    float inv = 1.0f / (sqrtf(ss) + 1e-12f);

    ushort4 st;
    st.x = f2bf(v.x * inv); st.y = f2bf(v.y * inv);
    st.z = f2bf(v.z * inv); st.w = f2bf(v.w * inv);

    int t = 0, dst = 0;
    if (lane == 0) { t = tgt[row]; dst = atomicAdd(&bincur[t], 1); }
    dst = __shfl(dst, 0); t = __shfl(t, 0);

    ((ushort4*)(xbs + (size_t)dst * DIM))[lane] = st;

    float a0 = bf2f(st.x), a1 = bf2f(st.y), a2 = bf2f(st.z), a3 = bf2f(st.w);
    float s2 = a0 * a0 + a1 * a1 + a2 * a2 + a3 * a3;
#pragma unroll
    for (int m = 1; m < 64; m <<= 1) s2 += __shfl_xor(s2, m, 64);
    if (lane == 0) {
        sqs[dst]  = s2;
        tgts[dst] = t;
        pmax[dst] = 0x007FFFFFu;  // f2ord(-inf)
        nmin[dst] = 0xFF800000u;  // f2ord(+inf)
    }
}

// K3: fused gram + hard-pos/hard-neg. Block: 4 waves, 256 rows x 512 cols.
// Grid (32,16) = 512 blocks at 2 blocks/CU (__launch_bounds__(256,2): VGPR 128
// + unified AGPRs, zero spill — R6/R7 proved 3-4 blocks/CU spills: demand is
// ~230 unified regs/wave). 8 stages of 64 cols (32KB/stage, double-buffered):
// half the barriers of R3.
//
// LDS layout (conflict-free): per (col-tile u, k-chunk kk) a 1KB block at
// u*8192 + kk*1024; lane L's b128 fragment sits at +L*16 (contiguous-per-lane,
// m134 best case ~12cyc, no xor addressing: ONE address reg + immediate
// offsets). The DMA produces this directly: instruction (u,kk), lane L fetches
// global row (n0+u*16+(L&15)), bytes (L>>4)*16 + kk*64 — lane-constant offset.
// R3's 16B xor swizzle was 8-way phase-aliased (l15*512 = 0 mod 32 banks):
// 2.1M conflict cycles.
__global__ __launch_bounds__(256, 2) void gram_kernel(
    const ushort* __restrict__ xbs, const float* __restrict__ sqs,
    const int* __restrict__ tgts, unsigned* __restrict__ pmax,
    unsigned* __restrict__ nmin)
{
    __shared__ struct {
        char  buf[2][32768];   // stage buffers: 64 cols, blocked (u,kk,lane)
        float sqc[512];        // per-col ||x||^2 for this 512-col chunk
        int   tgc[512];        // per-col class
        int   tga[256];        // per-row class for block's 256 rows
    } sm;

    const int wave = threadIdx.x >> 6;
    const int lane = threadIdx.x & 63;
    const int l15  = lane & 15;
    const int quad = lane >> 4;
    const int mbase = blockIdx.x * 256 + wave * 64;
    const int nbase = blockIdx.y * 512;

    {   // stage metadata for the chunk
        int c = threadIdx.x * 2;
        sm.sqc[c]     = sqs[nbase + c];
        sm.sqc[c + 1] = sqs[nbase + c + 1];
        sm.tgc[c]     = tgts[nbase + c];
        sm.tgc[c + 1] = tgts[nbase + c + 1];
        sm.tga[threadIdx.x] = tgts[blockIdx.x * 256 + threadIdx.x];
    }

    // Preload A fragments: 4 tiles x full K=256 (sorted storage, direct).
    bf16x8 afrag[4][8];
#pragma unroll
    for (int a = 0; a < 4; ++a) {
        const ushort* arow = xbs + (size_t)(mbase + a * 16 + l15) * DIM + quad * 8;
#pragma unroll
        for (int kk = 0; kk < 8; ++kk)
            afrag[a][kk] = *(const bf16x8*)(arow + kk * 32);
    }
    const int rlo = tgts[mbase];
    const int rhi = tgts[mbase + 63];

    // Lane-constant DMA source offset: row (l15) stride 512B, quad picks 16B.
    const int loff = l15 * 512 + quad * 16;
    const char* xbs_b = (const char*)xbs;

    // Wave w stages col-tile u=w of each stage: 8 DMA instructions (kk=0..7).
    {   // prologue: stage 0 (cols nbase .. nbase+63)
        const char* gsrc = xbs_b + (size_t)(nbase + wave * 16) * 512 + loff;
        char* ldst = sm.buf[0] + wave * 8192;
#pragma unroll
        for (int kk = 0; kk < 8; ++kk)
            ld16_g2l(gsrc + kk * 64, ldst + kk * 1024);
    }
    __syncthreads();   // drains prologue DMA + metadata stores

    float pm[16], nm[16];
#pragma unroll
    for (int j = 0; j < 16; ++j) { pm[j] = -__builtin_inff(); nm[j] = __builtin_inff(); }

#pragma unroll 2
    for (int s = 0; s < 8; ++s) {
        if (s < 7) {   // issue stage s+1; lands during this stage's compute
            const char* gsrc = xbs_b + (size_t)(nbase + (s + 1) * 64 + wave * 16) * 512 + loff;
            char* ldst = sm.buf[(s + 1) & 1] + wave * 8192;
#pragma unroll
            for (int kk = 0; kk < 8; ++kk)
                ld16_g2l(gsrc + kk * 64, ldst + kk * 1024);
        }
        // One address reg (+ immediate offsets) for ALL ds_read_b128 this stage.
        const char* bb = sm.buf[s & 1] + lane * 16;
#pragma unroll
        for (int u = 0; u < 4; ++u) {
            const int t16 = s * 64 + u * 16;
            bf16x8 bfrag[8];
#pragma unroll
            for (int kk = 0; kk < 8; ++kk)
                bfrag[kk] = *(const bf16x8*)(bb + u * 8192 + kk * 1024);
            f32x4 acc4[4];
#pragma unroll
            for (int a = 0; a < 4; ++a) {
                f32x4 acc = {0.f, 0.f, 0.f, 0.f};
#pragma unroll
                for (int kk = 0; kk < 8; ++kk)
                    acc = __builtin_amdgcn_mfma_f32_16x16x32_bf16(afrag[a][kk], bfrag[kk], acc, 0, 0, 0);
                acc4[a] = acc;
            }
            const float sqc = sm.sqc[t16 + l15];
            const int clo = sm.tgc[t16], chi = sm.tgc[t16 + 15];
            if (rlo <= chi && clo <= rhi) {
                const int tc = sm.tgc[t16 + l15];
#pragma unroll
                for (int a = 0; a < 4; ++a)
#pragma unroll
                    for (int i = 0; i < 4; ++i) {
                        const float v = fmaf(acc4[a][i], -2.0f, sqc);
                        const bool same = (sm.tga[wave * 64 + a * 16 + quad * 4 + i] == tc);
                        pm[a * 4 + i] = fmaxf(pm[a * 4 + i], same ? v : -__builtin_inff());
                        nm[a * 4 + i] = fminf(nm[a * 4 + i], same ? __builtin_inff() : v);
                    }
            } else {
#pragma unroll
                for (int a = 0; a < 4; ++a)
#pragma unroll
                    for (int i = 0; i < 4; ++i)
                        nm[a * 4 + i] = fminf(nm[a * 4 + i], fmaf(acc4[a][i], -2.0f, sqc));
            }
        }
        __syncthreads();
    }

    // Reduce across the 16 column-lanes, one atomic per row.
#pragma unroll
    for (int m = 1; m < 16; m <<= 1) {
#pragma unroll
        for (int j = 0; j < 16; ++j) {
            pm[j] = fmaxf(pm[j], __shfl_xor(pm[j], m, 64));
            nm[j] = fminf(nm[j], __shfl_xor(nm[j], m, 64));
        }
    }
    if (l15 == 0) {
#pragma unroll
        for (int a = 0; a < 4; ++a)
#pragma unroll
            for (int i = 0; i < 4; ++i) {
                int r = mbase + a * 16 + quad * 4 + i;
                atomicMax(&pmax[r], f2ord(pm[a * 4 + i]));
                atomicMin(&nmin[r], f2ord(nm[a * 4 + i]));
            }
    }
}

// K4: multi-block finalize, fp64 atomic accumulation + completion ticket.
__global__ __launch_bounds__(256) void finalize_kernel(
    const unsigned* __restrict__ pmax, const unsigned* __restrict__ nmin,
    const float* __restrict__ sqs, double* __restrict__ accd,
    unsigned* __restrict__ ticket, float* __restrict__ out)
{
    int r = blockIdx.x * 256 + threadIdx.x;
    float pe = ord2f(pmax[r]);
    float ne = ord2f(nmin[r]);
    float ap = sqrtf(fmaxf(sqs[r] + pe, 0.0f));
    float an = (ne > 1e30f) ? (MARGIN + 1.0f) : sqrtf(fmaxf(sqs[r] + ne, 0.0f));
    float h  = fmaxf(ap - an + MARGIN, 0.0f);
    double s = (double)h;
#pragma unroll
    for (int m = 1; m < 64; m <<= 1) s += __shfl_xor(s, m, 64);
    __shared__ double sh[4];
    if ((threadIdx.x & 63) == 0) sh[threadIdx.x >> 6] = s;
    __syncthreads();
    if (threadIdx.x == 0) {
        double b = sh[0] + sh[1] + sh[2] + sh[3];
        atomicAdd(accd, b);
        __threadfence();
        unsigned old = atomicAdd(ticket, 1u);
        if (old == gridDim.x - 1) {
            double total = atomicAdd(accd, 0.0);  // coherent read
            out[0] = (float)(total / (double)NROWS);
        }
    }
}

extern "C" void kernel_launch(void* const* d_in, const int* in_sizes, int n_in,
                              void* d_out, int out_size, void* d_ws, size_t ws_size,
                              hipStream_t stream) {
    const float* in  = (const float*)d_in[0];
    const int*   tgt = (const int*)d_in[1];
    float*       out = (float*)d_out;

    char* ws = (char*)d_ws;
    ushort*   xbs    = (ushort*)(ws + XBS_OFF);
    float*    sqs    = (float*)(ws + SQS_OFF);
    int*      tgts   = (int*)(ws + TGT_OFF);
    unsigned* pmax   = (unsigned*)(ws + PMX_OFF);
    unsigned* nmin   = (unsigned*)(ws + NMN_OFF);
    int*      bincur = (int*)(ws + BIN_OFF);
    double*   accd   = (double*)(ws + ACC_OFF);
    unsigned* ticket = (unsigned*)(ws + TIK_OFF);

    hist_scan_kernel<<<1, 512, 0, stream>>>(tgt, bincur, accd, ticket);
    norm_scatter_kernel<<<NROWS / 4, 256, 0, stream>>>(in, tgt, bincur, xbs, sqs, tgts, pmax, nmin);
    gram_kernel<<<dim3(32, 16), 256, 0, stream>>>(xbs, sqs, tgts, pmax, nmin);
    finalize_kernel<<<32, 256, 0, stream>>>(pmax, nmin, sqs, accd, ticket, out);
}